// Round 7
// baseline (232.861 us; speedup 1.0000x reference)
//
#include <hip/hip_runtime.h>

// LIF forward: X [B, T, N] fp32 -> spikes [B, T, N] fp32
// B=128, T=32, N=8192.
//   mem = mem + (x - mem)/2 ; spike = (mem-1 > 0) ; mem = spike ? 0 : mem
// Memory-bound. WRITE_SIZE=134 MB exact; FETCH_SIZE=65.6 MB (input half
// L3-resident) -> HBM floor ~31-40 us. Harness dur = kernel + ~160 us of
// 512 MiB poison fills (which run at 6.5-6.7 TB/s -> proves the chip).
// R1/R9/R10: every VGPR-held float4 burst variant -> 84-85 us; allocator
//     serializes the in-flight window (VGPR_Count 24-36, impossible for
//     the intended liveness). Inline-asm loads retired.
// R5/R6: asm dwordx2 burst ~62 us; R6 counted waits NEUTRAL -> intra-wave
//     schedule is not the lever. R7/R8: asm stores FAIL (store-data
//     hazard) -> retired.
// R11: zero-asm straight-line 32 plain float2 loads: ~66 us. R5-class.
// Pattern: ALL register-burst designs cap at 2.4-3.2 TB/s vs 6.3-6.7
//     TB/s demonstrated by fills/copy on this same memory system.
// R12 (this): global_load_lds DMA staging -- the one gfx950 mechanism
//     that issues deep bursts WITHOUT destination VGPRs (allocator can't
//     serialize what it doesn't allocate). Per 256-thread block: 4
//     autonomous waves (no s_barrier), each owns a 16 KB LDS strip
//     sm[wid][16][64] and one f32x4 column of 64 lanes. Per half (16
//     timesteps): issue 16 global_load_lds (1 KB/instr, coalesced; LDS
//     dest = wave-uniform base + lane*16 per m104) -> s_waitcnt vmcnt(0)
//     -> per row: ds_read_b128 (lane-consecutive, free 2-way bank
//     pattern), scan, plain store. Strip reuse across halves is safe:
//     each h0 ds_read completes before its dependent store issues, which
//     precedes h1's DMA in program order; "memory"-clobber asm wait
//     orders LDS reads vs the wait (reads are memory ops, unlike rule
//     #18's register-only MFMA case).
//     LDS 64 KB/block -> 2 blocks/CU, 8 waves/CU; in-flight up to 128
//     KB/CU >> ~22 KB Little's-law need at ~900 cy.
//     SIGNATURE: LDS_Block_Size=65536, VGPR ~32-48, kernel ~45-58 us.
//     If still ~62-66 us with guaranteed depth -> strided-row pattern
//     ceiling, declare roofline.

typedef float f32x4 __attribute__((ext_vector_type(4)));

#define T_STEPS 32
#define N4 2048           // f32x4 elements per (b,t) row (N/4)
#define TN4 (T_STEPS * N4)

__global__ __launch_bounds__(256) void lif_fwd_kernel(
    const f32x4* __restrict__ X, f32x4* __restrict__ out)
{
    // Per-wave strips: 4 waves x 16 rows x 64 lanes x 16 B = 64 KB.
    __shared__ f32x4 sm[4][16][64];

    const int tid  = threadIdx.x;
    const int wid  = tid >> 6;
    const int lane = tid & 63;

    const int b   = blockIdx.x >> 3;                 // 8 blocks per batch
    const int col = ((blockIdx.x & 7) << 8) + tid;   // f32x4 column in [0,2048)
    const size_t base = (size_t)b * (size_t)TN4 + (size_t)col;

    const f32x4* gp = X + base;
    f32x4* __restrict__ po = out + base;

    float m0 = 0.f, m1 = 0.f, m2 = 0.f, m3 = 0.f;

#pragma unroll
    for (int h = 0; h < 2; ++h) {
        // ---- DMA-stage 16 rows into this wave's LDS strip. No dest
        // VGPRs: the allocator cannot serialize this burst. ----
#pragma unroll
        for (int r = 0; r < 16; ++r) {
            __builtin_amdgcn_global_load_lds(
                (const __attribute__((address_space(1))) void*)
                    (gp + (size_t)(h * 16 + r) * (size_t)N4),
                (__attribute__((address_space(3))) void*)(&sm[wid][r][0]),
                16, /*offset=*/0, /*aux=*/0);
        }

        // Drain the DMA (vmcnt tracks global_load_lds). Also drains the
        // previous half's stores -- harmless (R6: wait granularity is
        // neutral). "memory" clobber orders the LDS reads below.
        asm volatile("s_waitcnt vmcnt(0)" ::: "memory");

        // ---- Scan 16 timesteps from LDS + plain stores. ----
#pragma unroll
        for (int r = 0; r < 16; ++r) {
            const f32x4 x = sm[wid][r][lane];

            // exact reference order: mem += (x - mem) * 0.5 ; threshold 1.0
            m0 = m0 + (x.x - m0) * 0.5f;
            m1 = m1 + (x.y - m1) * 0.5f;
            m2 = m2 + (x.z - m2) * 0.5f;
            m3 = m3 + (x.w - m3) * 0.5f;

            f32x4 s;
            s.x = (m0 - 1.0f > 0.0f) ? 1.0f : 0.0f;
            s.y = (m1 - 1.0f > 0.0f) ? 1.0f : 0.0f;
            s.z = (m2 - 1.0f > 0.0f) ? 1.0f : 0.0f;
            s.w = (m3 - 1.0f > 0.0f) ? 1.0f : 0.0f;

            m0 = (s.x != 0.0f) ? 0.0f : m0;
            m1 = (s.y != 0.0f) ? 0.0f : m1;
            m2 = (s.z != 0.0f) ? 0.0f : m2;
            m3 = (s.w != 0.0f) ? 0.0f : m3;

            po[(size_t)(h * 16 + r) * (size_t)N4] = s;
        }
    }
}

extern "C" void kernel_launch(void* const* d_in, const int* in_sizes, int n_in,
                              void* d_out, int out_size, void* d_ws, size_t ws_size,
                              hipStream_t stream) {
    const f32x4* X = (const f32x4*)d_in[0];
    f32x4* out = (f32x4*)d_out;

    const int total = in_sizes[0];          // B*T*N = 33554432 elements
    const int B = total / (T_STEPS * 8192); // 128
    const int nthreads = B * N4;            // 262144

    const int block = 256;
    const int grid = (nthreads + block - 1) / block;  // 1024 = 2/CU x 2 gens

    lif_fwd_kernel<<<grid, block, 0, stream>>>(X, out);
}

// Round 10
// 225.869 us; speedup vs baseline: 1.0310x; 1.0310x over previous
//
#include <hip/hip_runtime.h>

// LIF forward: X [B, T, N] fp32 -> spikes [B, T, N] fp32
// B=128, T=32, N=8192.
//   mem = mem + (x - mem)/2 ; spike = (mem-1 > 0) ; mem = spike ? 0 : mem
// Measured as LATENCY-bound: VALUBusy ~5%, MfmaUtil 0, Occupancy 15-30%,
// HBM ~2.4-3.3 TB/s vs 6.7 TB/s fills on the same profile.
// Harness dur = kernel + ~160 us of 512 MiB poison fills.
// History:
// R1/R9/R10: VGPR-held float4 bursts -> 84-85 us (allocator serializes).
// R5/R6: asm dwordx2 burst ~62-63 us; counted waits NEUTRAL.
// R7/R8: asm stores FAIL (VMEM store-data hazard) -> asm stores retired.
// R11: zero-asm straight-line float2, bounds(256,2): ~66 us. Sound.
// R12: global_load_lds DMA staging, depth GUARANTEED: still 81 us.
//     FALSIFIES the in-flight-depth theory family (depth 1..16 KB/wave,
//     occupancy 8..24 waves/CU all ~6.5-8.3 GB/s read/CU).
// KEY STUCK COUNTER: FETCH_SIZE = 65.6 MB = exactly half the input,
//     every round. The output's 134 MB of write-ALLOCATIONS evicts the
//     input from the 256 MB L3 between harness iterations -> half the
//     reads pay full ~900 cy HBM latency.
// R13: nt-stores -- broker infra failure, never ran.
// R14: nt-stores -- COMPILE FAIL: __builtin_nontemporal_store rejects
//     HIP_vector_type float2* (needs scalar or clang-vector pointee).
// R15 (this): same experiment, clang ext_vector_type(2) f32x2 for the
//     data path (same 8-B layout; builtin accepts vector-of-float).
//     Structure = R11: straight-line 32 named loads, 32 compute+nt-store
//     steps, bounds(256,2), zero asm.
//     SIGNATURE: FETCH_SIZE 65.6 MB -> <10 MB, WRITE_SIZE 134 MB
//     unchanged, kernel ~66 -> 45-55 us. If FETCH collapses but time
//     doesn't: latency theory dead -> revert + declare roofline.

typedef float f32x2 __attribute__((ext_vector_type(2)));

#define T_STEPS 32
#define N2 4096           // N/2 f32x2 elements per (b,t) row
#define TN2 (T_STEPS * N2)

__global__ __launch_bounds__(256, 2) void lif_fwd_kernel(
    const f32x2* __restrict__ X, f32x2* __restrict__ out)
{
    const int idx = blockIdx.x * blockDim.x + threadIdx.x;  // over B * N2
    const int b = idx >> 12;          // / N2
    const int n = idx & (N2 - 1);
    const size_t base = (size_t)b * (size_t)TN2 + (size_t)n;

    const f32x2* __restrict__ p = X + base;
    f32x2* __restrict__ po = out + base;

    // ---- 32 plain loads, straight-line, named scalars (no array, no
    // loop, no asm). 256-VGPR budget -> no pressure reason to sink. ----
#define LD(i) const f32x2 x##i = p[(size_t)(i) * (size_t)N2]
    LD(0);  LD(1);  LD(2);  LD(3);  LD(4);  LD(5);  LD(6);  LD(7);
    LD(8);  LD(9);  LD(10); LD(11); LD(12); LD(13); LD(14); LD(15);
    LD(16); LD(17); LD(18); LD(19); LD(20); LD(21); LD(22); LD(23);
    LD(24); LD(25); LD(26); LD(27); LD(28); LD(29); LD(30); LD(31);
#undef LD

    float m0 = 0.f, m1 = 0.f;

    // ---- 32 scan steps + NON-TEMPORAL stores (no L3 write-allocate:
    // the output never evicts the input; reads stay L3-resident). ----
#define STEP(i) do {                                                        \
        m0 = m0 + (x##i.x - m0) * 0.5f;                                     \
        m1 = m1 + (x##i.y - m1) * 0.5f;                                     \
        f32x2 s;                                                            \
        s.x = (m0 - 1.0f > 0.0f) ? 1.0f : 0.0f;                             \
        s.y = (m1 - 1.0f > 0.0f) ? 1.0f : 0.0f;                             \
        m0 = (s.x != 0.0f) ? 0.0f : m0;                                     \
        m1 = (s.y != 0.0f) ? 0.0f : m1;                                     \
        __builtin_nontemporal_store(s, po + (size_t)(i) * (size_t)N2);      \
    } while (0)
    STEP(0);  STEP(1);  STEP(2);  STEP(3);  STEP(4);  STEP(5);  STEP(6);  STEP(7);
    STEP(8);  STEP(9);  STEP(10); STEP(11); STEP(12); STEP(13); STEP(14); STEP(15);
    STEP(16); STEP(17); STEP(18); STEP(19); STEP(20); STEP(21); STEP(22); STEP(23);
    STEP(24); STEP(25); STEP(26); STEP(27); STEP(28); STEP(29); STEP(30); STEP(31);
#undef STEP
}

extern "C" void kernel_launch(void* const* d_in, const int* in_sizes, int n_in,
                              void* d_out, int out_size, void* d_ws, size_t ws_size,
                              hipStream_t stream) {
    const f32x2* X = (const f32x2*)d_in[0];
    f32x2* out = (f32x2*)d_out;

    const int total = in_sizes[0];          // B*T*N = 33554432 elements
    const int B = total / (T_STEPS * 8192); // 128
    const int nthreads = B * N2;            // 524288

    const int block = 256;
    const int grid = (nthreads + block - 1) / block;  // 2048

    lif_fwd_kernel<<<grid, block, 0, stream>>>(X, out);
}